// Round 6
// baseline (260.585 us; speedup 1.0000x reference)
//
#include <hip/hip_runtime.h>

// YOLOv1 loss, faithful to the reference (including the in-place corner bug).
// R11b: same experiment as R11 (nt-load A/B vs R7), with the compile fix:
// __builtin_nontemporal_load requires a clang ext_vector_type, not HIP's
// float2 wrapper class.
//   Evidence so far: R6/R7/R8/R9 (staged-T, strided-regs, gload_lds drained,
//   gload_lds pipelined; occupancy 11%..61%) ALL deliver ~2.6 TB/s read-only.
//   R10's spill accident showed ~3.15 TB/s aggregate with mixed read+write.
//   Little's law at ~900 cy miss latency -> ~60 outstanding lines/CU, i.e. a
//   per-CU L1 miss-tracking cap. nt loads (no-allocate/evict-first) test
//   whether bypassing L1 allocation lifts the clamp. If null, the read
//   service ceiling is structural: 192.7 MB / ~2.6-3.1 TB/s = 62-74 us floor.

typedef float vf2 __attribute__((ext_vector_type(2)));

constexpr int   BLK  = 256;
constexpr int   NC   = 16384 * 7 * 7;   // 802816 cells
constexpr int   GRID = NC / BLK;        // 3136 blocks, exact (no bounds check)
constexpr float CELL = 1.0f / 7.0f;
constexpr float LC   = 5.0f;
constexpr float LN   = 0.5f;

__launch_bounds__(BLK, 8)               // 8 waves/EU -> 32 waves/CU, VGPR <= 64
__global__ void yolo_partial(const float* __restrict__ P, const float* __restrict__ T,
                             float4* __restrict__ ws)
{
    const int tid  = threadIdx.x;
    const int cell = blockIdx.x * BLK + tid;
    const float* trow = T + (size_t)cell * 30;
    const float* prow = P + (size_t)cell * 30;

    // ---- one independent load batch: 15+5 nontemporal 8-B loads ----
    float tv[30];
    #pragma unroll
    for (int j = 0; j < 15; ++j) {
        vf2 v = __builtin_nontemporal_load(reinterpret_cast<const vf2*>(trow) + j);
        tv[2 * j] = v.x; tv[2 * j + 1] = v.y;
    }
    float pv[10];
    #pragma unroll
    for (int j = 0; j < 5; ++j) {
        vf2 v = __builtin_nontemporal_load(reinterpret_cast<const vf2*>(prow) + j);
        pv[2 * j] = v.x; pv[2 * j + 1] = v.y;
    }

    // class column: argmax over t[10:30], first occurrence (strict >)
    int kc = 10;
    float best = tv[10];
    #pragma unroll
    for (int k = 11; k < 30; ++k) {
        if (tv[k] > best) { best = tv[k]; kc = k; }
    }
    // dependent 8-B gather for p[kc] (kc in [10,30)); plain load
    float2 pg = *reinterpret_cast<const float2*>(prow + (kc & ~1));
    float pk = (kc & 1) ? pg.y : pg.x;

    const float t4 = tv[4];
    const float obj   = (t4 == 1.0f) ? 1.0f : 0.0f;
    const float noobj = (t4 == 0.0f) ? 1.0f : 0.0f;

    float d4 = pv[4] - t4;
    float d9 = pv[9] - tv[9];
    float a_noobj = noobj * (d4 * d4 + d9 * d9);

    // target corners (faithful bug: x2 uses already-updated x1)
    float tw2 = tv[2] * tv[2], th2 = tv[3] * tv[3];
    float tx1 = tv[0] * CELL - 0.5f * tw2;
    float tx2 = tx1 * CELL + 0.5f * tw2;
    float ty1 = tv[1] * CELL - 0.5f * th2;
    float ty2 = ty1 * CELL + 0.5f * th2;
    float area_t = (tx2 - tx1) * (ty2 - ty1);

    float iou0, iou1;
    #pragma unroll
    for (int b = 0; b < 2; ++b) {
        float bw2 = pv[5 * b + 2] * pv[5 * b + 2];
        float bh2 = pv[5 * b + 3] * pv[5 * b + 3];
        float px1 = pv[5 * b + 0] * CELL - 0.5f * bw2;
        float px2 = px1 * CELL + 0.5f * bw2;
        float py1 = pv[5 * b + 1] * CELL - 0.5f * bh2;
        float py2 = py1 * CELL + 0.5f * bh2;
        float ltx = fmaxf(px1, tx1), lty = fmaxf(py1, ty1);
        float rbx = fminf(px2, tx2), rby = fminf(py2, ty2);
        float inter = fmaxf(rbx - ltx, 0.0f) * fmaxf(rby - lty, 0.0f);
        float area_p = (px2 - px1) * (py2 - py1);
        float iou = inter / (area_p + area_t - inter);
        if (b == 0) iou0 = iou; else iou1 = iou;
    }
    const bool b1 = (iou1 > iou0);   // jnp.argmax: first on ties

    float cpx = b1 ? pv[5] : pv[0], ctx = b1 ? tv[5] : tv[0];
    float cpy = b1 ? pv[6] : pv[1], cty = b1 ? tv[6] : tv[1];
    float cpw = b1 ? pv[7] : pv[2], ctw = b1 ? tv[7] : tv[2];
    float cph = b1 ? pv[8] : pv[3], cth = b1 ? tv[8] : tv[3];
    float cpc = b1 ? pv[9] : pv[4], ctc = b1 ? tv[9] : tv[4];

    float dx = cpx - ctx, dy = cpy - cty;
    float dw = cpw - ctw, dh = cph - cth;
    float a_cw   = obj * (dx * dx + dy * dy + dw * dw + dh * dh);
    float dc = cpc - ctc;
    float a_conf = obj * dc * dc;
    float dk = pk - best;
    float a_cls  = obj * dk * dk;

    // ---- block reduction: wave shuffle -> tiny LDS across 4 waves ----
    float vals[4] = { a_cls, a_conf, a_cw, a_noobj };
    #pragma unroll
    for (int c = 0; c < 4; ++c) {
        #pragma unroll
        for (int off = 32; off > 0; off >>= 1)
            vals[c] += __shfl_down(vals[c], off, 64);
    }
    __shared__ float red[4][4];
    const int wave = tid >> 6;
    if ((tid & 63) == 0) {
        red[0][wave] = vals[0]; red[1][wave] = vals[1];
        red[2][wave] = vals[2]; red[3][wave] = vals[3];
    }
    __syncthreads();
    if (tid == 0) {
        ws[blockIdx.x] = make_float4(
            red[0][0] + red[0][1] + red[0][2] + red[0][3],
            red[1][0] + red[1][1] + red[1][2] + red[1][3],
            red[2][0] + red[2][1] + red[2][2] + red[2][3],
            red[3][0] + red[3][1] + red[3][2] + red[3][3]);
    }
}

__launch_bounds__(1024, 1)
__global__ void yolo_reduce(const float4* __restrict__ ws, float* __restrict__ out)
{
    __shared__ float red[4][16];
    const int tid = threadIdx.x;

    float s0 = 0.f, s1 = 0.f, s2 = 0.f, s3 = 0.f;
    for (int b = tid; b < GRID; b += 1024) {    // coalesced float4 stream
        float4 v = ws[b];
        s0 += v.x; s1 += v.y; s2 += v.z; s3 += v.w;
    }
    float vals[4] = { s0, s1, s2, s3 };
    #pragma unroll
    for (int c = 0; c < 4; ++c) {
        #pragma unroll
        for (int off = 32; off > 0; off >>= 1)
            vals[c] += __shfl_down(vals[c], off, 64);
        if ((tid & 63) == 0) red[c][tid >> 6] = vals[c];
    }
    __syncthreads();
    if (tid == 0) {
        float t0 = 0.f, t1 = 0.f, t2 = 0.f, t3 = 0.f;
        #pragma unroll
        for (int w = 0; w < 16; ++w) {
            t0 += red[0][w]; t1 += red[1][w]; t2 += red[2][w]; t3 += red[3][w];
        }
        out[0] = LC * t0;                              // cls_loss
        out[1] = LC * t1;                              // conf_loss
        out[2] = LC * t2;                              // center+wh
        out[3] = LN * t3 + LC * (t0 + t1 + t2);        // total
    }
}

extern "C" void kernel_launch(void* const* d_in, const int* in_sizes, int n_in,
                              void* d_out, int out_size, void* d_ws, size_t ws_size,
                              hipStream_t stream) {
    const float* P = (const float*)d_in[0];
    const float* T = (const float*)d_in[1];
    float* out = (float*)d_out;
    float4* ws = (float4*)d_ws;          // GRID * 16 B = 50176 B of scratch

    yolo_partial<<<GRID, BLK, 0, stream>>>(P, T, ws);
    yolo_reduce<<<1, 1024, 0, stream>>>(ws, out);
}

// Round 7
// 205.586 us; speedup vs baseline: 1.2675x; 1.2675x over previous
//
#include <hip/hip_runtime.h>

// YOLOv1 loss, faithful to the reference (including the in-place corner bug).
// R12: one-variable A/B vs R8 -- identical structure (128-cell tile, 30720 B
// LDS, 3136 blocks x 2 tiles, same compute/barriers); ONLY the staging path
// changes: plain coalesced global_load_dwordx4 -> VGPR -> ds_write_b128,
// instead of the global_load_lds DMA engine.
//   Evidence: R7 (plain path, strided) 73us; R8/R9 (coalesced, gload_lds,
//   drained/pipelined) 74us; R11b (nt, HBM-only service) 2.18 TB/s. All
//   read-dominated configs pin at ~2.1-2.6 TB/s. Untested cell = coalesced +
//   plain path (m13's proven 6.29 TB/s shape). Mechanism under test:
//   gload_lds returns are buffered in-order per CU (small outstanding-miss
//   window); plain loads return to per-lane VGPR slots at full miss BW.
//   Single-buffered r[15] (no cross-iteration liveness -> no R10 spill trap).
//   Pre-commit: null result (70-78us) => declare roofline.

constexpr int   BLK   = 128;            // 2 waves
constexpr int   TILE  = 128;            // cells per tile (1 cell/thread)
constexpr int   NC    = 16384 * 7 * 7;  // 802816 cells
constexpr int   NTILE = NC / TILE;      // 6272 tiles
constexpr int   GRID  = 3136;           // 2 tiles per block, exact
constexpr float CELL  = 1.0f / 7.0f;
constexpr float LC    = 5.0f;
constexpr float LN    = 0.5f;

__launch_bounds__(BLK, 4)               // VGPR cap 128 (peak ~90, no spills)
__global__ void yolo_partial(const float* __restrict__ P, const float* __restrict__ T,
                             float4* __restrict__ ws)
{
    // [0,960) float4 = T tile (128 cells x 120 B), [960,1920) = P tile
    __shared__ float4 s4[1920];         // 30720 B -> 5 blocks/CU
    __shared__ float red[4][2];

    const int tid = threadIdx.x;
    float a_cls = 0.f, a_conf = 0.f, a_cw = 0.f, a_noobj = 0.f;

    for (int t = blockIdx.x; t < NTILE; t += GRID) {
        const size_t fbase = (size_t)t * (TILE * 30);   // float offset of tile
        const float4* gT = reinterpret_cast<const float4*>(T + fbase);
        const float4* gP = reinterpret_cast<const float4*>(P + fbase);

        // ---- staging: 15 plain coalesced dwordx4 loads -> VGPRs ----
        //      all 15 issued back-to-back (independent); per-lane return slots
        float4 r[15];
        #pragma unroll
        for (int k = 0; k < 15; ++k) {
            const int idx = k * BLK + tid;              // 0..1919
            r[k] = (idx < 960) ? gT[idx] : gP[idx - 960];
        }
        // ---- VGPR -> LDS (ds_write_b128, lane-contiguous, conflict-free) ----
        #pragma unroll
        for (int k = 0; k < 15; ++k)
            s4[k * BLK + tid] = r[k];
        __syncthreads();                // tile resident in LDS

        // ---- this thread's cell: 30 ds_read_b64 (T row + P row) ----
        const float* sf  = reinterpret_cast<const float*>(s4);
        const float* myT = sf + (size_t)tid * 30;
        const float* myP = sf + 3840 + (size_t)tid * 30;
        float tv[30], pv[30];
        #pragma unroll
        for (int j = 0; j < 15; ++j) {
            float2 a = reinterpret_cast<const float2*>(myT)[j];
            tv[2 * j] = a.x; tv[2 * j + 1] = a.y;
            float2 b = reinterpret_cast<const float2*>(myP)[j];
            pv[2 * j] = b.x; pv[2 * j + 1] = b.y;
        }

        // argmax over t[10:30] with p-payload, first occurrence (strict >)
        float best = tv[10], pk = pv[10];
        #pragma unroll
        for (int k = 11; k < 30; ++k) {
            if (tv[k] > best) { best = tv[k]; pk = pv[k]; }
        }

        const float t4    = tv[4];
        const float obj   = (t4 == 1.0f) ? 1.0f : 0.0f;
        const float noobj = (t4 == 0.0f) ? 1.0f : 0.0f;

        float d4 = pv[4] - t4;
        float d9 = pv[9] - tv[9];
        a_noobj += noobj * (d4 * d4 + d9 * d9);

        // target corners (faithful bug: x2 uses already-updated x1)
        float tw2 = tv[2] * tv[2], th2 = tv[3] * tv[3];
        float tx1 = tv[0] * CELL - 0.5f * tw2;
        float tx2 = tx1 * CELL + 0.5f * tw2;
        float ty1 = tv[1] * CELL - 0.5f * th2;
        float ty2 = ty1 * CELL + 0.5f * th2;
        float area_t = (tx2 - tx1) * (ty2 - ty1);

        float iou0, iou1;
        #pragma unroll
        for (int b = 0; b < 2; ++b) {
            float bw2 = pv[5 * b + 2] * pv[5 * b + 2];
            float bh2 = pv[5 * b + 3] * pv[5 * b + 3];
            float px1 = pv[5 * b + 0] * CELL - 0.5f * bw2;
            float px2 = px1 * CELL + 0.5f * bw2;
            float py1 = pv[5 * b + 1] * CELL - 0.5f * bh2;
            float py2 = py1 * CELL + 0.5f * bh2;
            float ltx = fmaxf(px1, tx1), lty = fmaxf(py1, ty1);
            float rbx = fminf(px2, tx2), rby = fminf(py2, ty2);
            float inter = fmaxf(rbx - ltx, 0.0f) * fmaxf(rby - lty, 0.0f);
            float area_p = (px2 - px1) * (py2 - py1);
            float iou = inter / (area_p + area_t - inter);
            if (b == 0) iou0 = iou; else iou1 = iou;
        }
        const bool b1 = (iou1 > iou0);   // jnp.argmax: first on ties

        float cpx = b1 ? pv[5] : pv[0], ctx = b1 ? tv[5] : tv[0];
        float cpy = b1 ? pv[6] : pv[1], cty = b1 ? tv[6] : tv[1];
        float cpw = b1 ? pv[7] : pv[2], ctw = b1 ? tv[7] : tv[2];
        float cph = b1 ? pv[8] : pv[3], cth = b1 ? tv[8] : tv[3];
        float cpc = b1 ? pv[9] : pv[4], ctc = b1 ? tv[9] : tv[4];

        float dx = cpx - ctx, dy = cpy - cty;
        float dw = cpw - ctw, dh = cph - cth;
        a_cw   += obj * (dx * dx + dy * dy + dw * dw + dh * dh);
        float dc = cpc - ctc;
        a_conf += obj * dc * dc;
        float dk = pk - best;
        a_cls  += obj * dk * dk;

        __syncthreads();                 // LDS consumed before next staging
    }

    // ---- block reduction: wave shuffle -> 2-wave LDS combine ----
    float vals[4] = { a_cls, a_conf, a_cw, a_noobj };
    #pragma unroll
    for (int c = 0; c < 4; ++c) {
        #pragma unroll
        for (int off = 32; off > 0; off >>= 1)
            vals[c] += __shfl_down(vals[c], off, 64);
    }
    const int wave = tid >> 6;
    if ((tid & 63) == 0) {
        red[0][wave] = vals[0]; red[1][wave] = vals[1];
        red[2][wave] = vals[2]; red[3][wave] = vals[3];
    }
    __syncthreads();
    if (tid == 0) {
        ws[blockIdx.x] = make_float4(red[0][0] + red[0][1],
                                     red[1][0] + red[1][1],
                                     red[2][0] + red[2][1],
                                     red[3][0] + red[3][1]);
    }
}

__launch_bounds__(1024, 1)
__global__ void yolo_reduce(const float4* __restrict__ ws, float* __restrict__ out)
{
    __shared__ float red[4][16];
    const int tid = threadIdx.x;

    float s0 = 0.f, s1 = 0.f, s2 = 0.f, s3 = 0.f;
    for (int b = tid; b < GRID; b += 1024) {    // coalesced float4 stream
        float4 v = ws[b];
        s0 += v.x; s1 += v.y; s2 += v.z; s3 += v.w;
    }
    float vals[4] = { s0, s1, s2, s3 };
    #pragma unroll
    for (int c = 0; c < 4; ++c) {
        #pragma unroll
        for (int off = 32; off > 0; off >>= 1)
            vals[c] += __shfl_down(vals[c], off, 64);
        if ((tid & 63) == 0) red[c][tid >> 6] = vals[c];
    }
    __syncthreads();
    if (tid == 0) {
        float t0 = 0.f, t1 = 0.f, t2 = 0.f, t3 = 0.f;
        #pragma unroll
        for (int w = 0; w < 16; ++w) {
            t0 += red[0][w]; t1 += red[1][w]; t2 += red[2][w]; t3 += red[3][w];
        }
        out[0] = LC * t0;                              // cls_loss
        out[1] = LC * t1;                              // conf_loss
        out[2] = LC * t2;                              // center+wh
        out[3] = LN * t3 + LC * (t0 + t1 + t2);        // total
    }
}

extern "C" void kernel_launch(void* const* d_in, const int* in_sizes, int n_in,
                              void* d_out, int out_size, void* d_ws, size_t ws_size,
                              hipStream_t stream) {
    const float* P = (const float*)d_in[0];
    const float* T = (const float*)d_in[1];
    float* out = (float*)d_out;
    float4* ws = (float4*)d_ws;          // GRID * 16 B = 50176 B of scratch

    yolo_partial<<<GRID, BLK, 0, stream>>>(P, T, ws);
    yolo_reduce<<<1, 1024, 0, stream>>>(ws, out);
}